// Round 1
// 109.923 us; speedup vs baseline: 1.0281x; 1.0281x over previous
//
#include <hip/hip_runtime.h>
#include <math.h>

// FeatureSqueezer: quantize trunc(x*scale)/scale + 3x3 median, reflect pad=1.
// x: (16, 1024, 1024) fp32. HBM floor: 128 MB -> ~21 us @ 6.3 TB/s (copy mix).
//
// Round-9 = round-8 with TY 4 -> 8. rocprof showed the kernel itself is ~27us
// (absent from top-5; fills are 43us each), i.e. ~78% of copy BW. Remaining
// headroom is halo amplification (6 rows loaded per 4 output rows = 1.5x) and
// per-block fixed cost. TY=8 loads 10 rows per 8 outputs (1.25x) and halves
// the per-row share of edge-lane loads / prologue. VGPR ~95, no spill,
// >=4 waves/SIMD — still plenty of MLP for a BW-bound kernel.
//  - full 10-row raw batch prefetch (max MLP)
//  - median BEFORE quantize (monotone trunc(x*s)/s commutes with order stats)
//  - column triples via v_min3/v_med3/v_max3; merge:
//      med9 = med3( max3(lows), med3(mids), min3(highs) )
//  - horizontal halo via in-wave shuffle; wave-edge lanes fetch one
//    exec-masked dword per row (reflect folded into address math)
//  - nontemporal output stores (write-once stream, keep L2/L3 for halo rows)

constexpr int H = 1024;
constexpr int W = 1024;
constexpr int TY = 8;            // output rows per block
constexpr int NR = TY + 2;       // prefetched rows

typedef float v4f __attribute__((ext_vector_type(4)));

__device__ __forceinline__ float min3f(float a, float b, float c) { return fminf(a, fminf(b, c)); }
__device__ __forceinline__ float max3f(float a, float b, float c) { return fmaxf(a, fmaxf(b, c)); }
__device__ __forceinline__ float med3f(float a, float b, float c) { return __builtin_amdgcn_fmed3f(a, b, c); }

__global__ __launch_bounds__(256) void fsq_kernel(const float* __restrict__ x,
                                                  const int* __restrict__ bdp,
                                                  float* __restrict__ out) {
    const int t    = threadIdx.x;          // 0..255 -> output cols 4t..4t+3
    const int lane = t & 63;
    const int y0   = blockIdx.x * TY;
    const int b    = blockIdx.y;

    const float q     = (float)((1 << bdp[0]) - 1);
    const float scale = 255.0f / q;
    const float rinv  = q / 255.0f;        // ~1/scale; quant error << 1.98e-2 threshold

    const size_t base = (size_t)b * H * W;
    const float* __restrict__ xb = x + base;
    float* __restrict__ ob       = out + base;

    const int c0 = 4 * t;
    // halo column wave-edge lanes fetch themselves (reflect folded in):
    const int cEdge = (lane == 0) ? ((c0 == 0) ? 1 : c0 - 1)
                                  : ((c0 + 4 < W) ? c0 + 4 : W - 2);
    const bool isEdge = (lane == 0) | (lane == 63);

    // ---- phase 1: issue ALL loads (raw values), maximal MLP ----
    v4f   m[NR];
    float e[NR];
    #pragma unroll
    for (int r = 0; r < NR; ++r) {
        int gy = y0 - 1 + r;
        gy = (gy < 0) ? 1 : ((gy >= H) ? 2 * H - 2 - gy : gy);     // reflect pad=1
        const float* row = xb + (size_t)gy * W;
        m[r] = *(const v4f*)(row + c0);                            // global_load_dwordx4
        e[r] = 0.0f;
        if (isEdge) e[r] = row[cEdge];                             // exec-masked dword
    }

    // ---- phase 2: shuffle raw halos, rolling 3-row median, quantize last ----
    float r0[6], r1[6], r2[6];

    auto mkrow = [&](int r, float* vv) {
        float l  = __shfl_up(m[r].w, 1, 64);                       // lane-1's col 4t-1
        float rr = __shfl_down(m[r].x, 1, 64);                     // lane+1's col 4t+4
        if (lane == 0)  l  = e[r];
        if (lane == 63) rr = e[r];
        vv[0] = l; vv[1] = m[r].x; vv[2] = m[r].y; vv[3] = m[r].z; vv[4] = m[r].w; vv[5] = rr;
    };

    mkrow(0, r0);
    mkrow(1, r1);

    #pragma unroll
    for (int i = 0; i < TY; ++i) {
        mkrow(2 + i, r2);

        // sort 6 vertical triples: (v_min3, v_med3, v_max3) on RAW values
        float lo[6], mi[6], hi[6];
        #pragma unroll
        for (int c = 0; c < 6; ++c) {
            lo[c] = min3f(r0[c], r1[c], r2[c]);
            mi[c] = med3f(r0[c], r1[c], r2[c]);
            hi[c] = max3f(r0[c], r1[c], r2[c]);
        }

        v4f o;
        o.x = med3f(max3f(lo[0], lo[1], lo[2]), med3f(mi[0], mi[1], mi[2]), min3f(hi[0], hi[1], hi[2]));
        o.y = med3f(max3f(lo[1], lo[2], lo[3]), med3f(mi[1], mi[2], mi[3]), min3f(hi[1], hi[2], hi[3]));
        o.z = med3f(max3f(lo[2], lo[3], lo[4]), med3f(mi[2], mi[3], mi[4]), min3f(hi[2], hi[3], hi[4]));
        o.w = med3f(max3f(lo[3], lo[4], lo[5]), med3f(mi[3], mi[4], mi[5]), min3f(hi[3], hi[4], hi[5]));

        // quantize the median (monotone f commutes with order statistics)
        o.x = truncf(o.x * scale) * rinv;
        o.y = truncf(o.y * scale) * rinv;
        o.z = truncf(o.z * scale) * rinv;
        o.w = truncf(o.w * scale) * rinv;
        __builtin_nontemporal_store(o, (v4f*)(ob + (size_t)(y0 + i) * W + c0));

        #pragma unroll
        for (int c = 0; c < 6; ++c) { r0[c] = r1[c]; r1[c] = r2[c]; }  // renamed by unroll
    }
}

extern "C" void kernel_launch(void* const* d_in, const int* in_sizes, int n_in,
                              void* d_out, int out_size, void* d_ws, size_t ws_size,
                              hipStream_t stream) {
    const float* x  = (const float*)d_in[0];
    const int*   bd = (const int*)d_in[1];
    float*       out = (float*)d_out;

    const int B = in_sizes[0] / (H * W);   // 16
    dim3 grid(H / TY, B);                  // (128, 16)
    fsq_kernel<<<grid, 256, 0, stream>>>(x, bd, out);
}

// Round 2
// 109.435 us; speedup vs baseline: 1.0327x; 1.0045x over previous
//
#include <hip/hip_runtime.h>
#include <math.h>

// FeatureSqueezer: quantize trunc(x*scale)/scale + 3x3 median, reflect pad=1.
// x: (16, 1024, 1024) fp32. HBM floor: 128 MB -> ~21.3 us @ 6.3 TB/s.
//
// Round-10 = round-9 with TY 8 -> 16. R9 post-mortem: harness 113.0->109.9,
// kernel ~27->~24 us (fills fixed at ~86 us) — halo-amortization theory held.
// One more step on the same lever: 18 rows loaded per 16 produced (1.125x
// amplification, was 1.25x), per-block prologue/edge cost halves. VGPR ~150
// -> ~3 waves/SIMD; with 18 outstanding dwordx4/wave the kernel stays
// BW-saturated (in-flight bytes/CU >> latency*BW/CU).
//  - full 18-row raw batch prefetch (max MLP)
//  - median BEFORE quantize (monotone trunc(x*s)/s commutes with order stats)
//  - column triples via v_min3/v_med3/v_max3; merge:
//      med9 = med3( max3(lows), med3(mids), min3(highs) )
//  - horizontal halo via in-wave shuffle; wave-edge lanes fetch one
//    exec-masked dword per row (reflect folded into address math)
//  - nontemporal output stores (write-once stream, keep L2/L3 for halo rows)

constexpr int H = 1024;
constexpr int W = 1024;
constexpr int TY = 16;           // output rows per block
constexpr int NR = TY + 2;       // prefetched rows

typedef float v4f __attribute__((ext_vector_type(4)));

__device__ __forceinline__ float min3f(float a, float b, float c) { return fminf(a, fminf(b, c)); }
__device__ __forceinline__ float max3f(float a, float b, float c) { return fmaxf(a, fmaxf(b, c)); }
__device__ __forceinline__ float med3f(float a, float b, float c) { return __builtin_amdgcn_fmed3f(a, b, c); }

__global__ __launch_bounds__(256) void fsq_kernel(const float* __restrict__ x,
                                                  const int* __restrict__ bdp,
                                                  float* __restrict__ out) {
    const int t    = threadIdx.x;          // 0..255 -> output cols 4t..4t+3
    const int lane = t & 63;
    const int y0   = blockIdx.x * TY;
    const int b    = blockIdx.y;

    const float q     = (float)((1 << bdp[0]) - 1);
    const float scale = 255.0f / q;
    const float rinv  = q / 255.0f;        // ~1/scale; quant error << 1.98e-2 threshold

    const size_t base = (size_t)b * H * W;
    const float* __restrict__ xb = x + base;
    float* __restrict__ ob       = out + base;

    const int c0 = 4 * t;
    // halo column wave-edge lanes fetch themselves (reflect folded in):
    const int cEdge = (lane == 0) ? ((c0 == 0) ? 1 : c0 - 1)
                                  : ((c0 + 4 < W) ? c0 + 4 : W - 2);
    const bool isEdge = (lane == 0) | (lane == 63);

    // ---- phase 1: issue ALL loads (raw values), maximal MLP ----
    v4f   m[NR];
    float e[NR];
    #pragma unroll
    for (int r = 0; r < NR; ++r) {
        int gy = y0 - 1 + r;
        gy = (gy < 0) ? 1 : ((gy >= H) ? 2 * H - 2 - gy : gy);     // reflect pad=1
        const float* row = xb + (size_t)gy * W;
        m[r] = *(const v4f*)(row + c0);                            // global_load_dwordx4
        e[r] = 0.0f;
        if (isEdge) e[r] = row[cEdge];                             // exec-masked dword
    }

    // ---- phase 2: shuffle raw halos, rolling 3-row median, quantize last ----
    float r0[6], r1[6], r2[6];

    auto mkrow = [&](int r, float* vv) {
        float l  = __shfl_up(m[r].w, 1, 64);                       // lane-1's col 4t-1
        float rr = __shfl_down(m[r].x, 1, 64);                     // lane+1's col 4t+4
        if (lane == 0)  l  = e[r];
        if (lane == 63) rr = e[r];
        vv[0] = l; vv[1] = m[r].x; vv[2] = m[r].y; vv[3] = m[r].z; vv[4] = m[r].w; vv[5] = rr;
    };

    mkrow(0, r0);
    mkrow(1, r1);

    #pragma unroll
    for (int i = 0; i < TY; ++i) {
        mkrow(2 + i, r2);

        // sort 6 vertical triples: (v_min3, v_med3, v_max3) on RAW values
        float lo[6], mi[6], hi[6];
        #pragma unroll
        for (int c = 0; c < 6; ++c) {
            lo[c] = min3f(r0[c], r1[c], r2[c]);
            mi[c] = med3f(r0[c], r1[c], r2[c]);
            hi[c] = max3f(r0[c], r1[c], r2[c]);
        }

        v4f o;
        o.x = med3f(max3f(lo[0], lo[1], lo[2]), med3f(mi[0], mi[1], mi[2]), min3f(hi[0], hi[1], hi[2]));
        o.y = med3f(max3f(lo[1], lo[2], lo[3]), med3f(mi[1], mi[2], mi[3]), min3f(hi[1], hi[2], hi[3]));
        o.z = med3f(max3f(lo[2], lo[3], lo[4]), med3f(mi[2], mi[3], mi[4]), min3f(hi[2], hi[3], hi[4]));
        o.w = med3f(max3f(lo[3], lo[4], lo[5]), med3f(mi[3], mi[4], mi[5]), min3f(hi[3], hi[4], hi[5]));

        // quantize the median (monotone f commutes with order statistics)
        o.x = truncf(o.x * scale) * rinv;
        o.y = truncf(o.y * scale) * rinv;
        o.z = truncf(o.z * scale) * rinv;
        o.w = truncf(o.w * scale) * rinv;
        __builtin_nontemporal_store(o, (v4f*)(ob + (size_t)(y0 + i) * W + c0));

        #pragma unroll
        for (int c = 0; c < 6; ++c) { r0[c] = r1[c]; r1[c] = r2[c]; }  // renamed by unroll
    }
}

extern "C" void kernel_launch(void* const* d_in, const int* in_sizes, int n_in,
                              void* d_out, int out_size, void* d_ws, size_t ws_size,
                              hipStream_t stream) {
    const float* x  = (const float*)d_in[0];
    const int*   bd = (const int*)d_in[1];
    float*       out = (float*)d_out;

    const int B = in_sizes[0] / (H * W);   // 16
    dim3 grid(H / TY, B);                  // (64, 16)
    fsq_kernel<<<grid, 256, 0, stream>>>(x, bd, out);
}